// Round 8
// baseline (47.142 us; speedup 1.0000x reference)
//
#include <hip/hip_runtime.h>
#include <hip/hip_bf16.h>

// C[M,N] = A[M,K] * B[K,N]; M=262144, K=N=128; fp32 in/out, bf16 MFMA.
// Memory-bound, ~4.4 TB/s effective at round 7. Round-8 probe: same total
// resident waves (16/CU, VGPR-capped) but 4 small block-pipelines per CU
// instead of 2 — TPB=256 (4 waves), BM=128, grid=2048, one tile per block —
// so block prologues (A/B stage latency) and epilogues (NT-store drain,
// which continues after s_endpgm while the next block launches) overlap
// across pipelines. If neutral: HBM-saturated -> roofline.

typedef __bf16 bf16x8 __attribute__((ext_vector_type(8)));
typedef float  f32x16 __attribute__((ext_vector_type(16)));
typedef unsigned short ushortx8 __attribute__((ext_vector_type(8)));

#define M_TOTAL (64 * 4096)       // 262144 rows
#define KDIM 128
#define NDIM 128
#define TPB 256                   // 4 waves
#define BM 128                    // rows per block (4 waves x 32 rows)
#define GRID (M_TOTAL / BM)       // 2048 blocks, 1 tile each

__device__ __forceinline__ bf16x8 cvt_frag(const float4 a0, const float4 a1) {
  bf16x8 af;
  af[0] = (__bf16)a0.x; af[1] = (__bf16)a0.y;
  af[2] = (__bf16)a0.z; af[3] = (__bf16)a0.w;
  af[4] = (__bf16)a1.x; af[5] = (__bf16)a1.y;
  af[6] = (__bf16)a1.z; af[7] = (__bf16)a1.w;
  return af;
}

__global__ __launch_bounds__(TPB) void emb_gemm_kernel(
    const float* __restrict__ A, const float* __restrict__ Emb,
    float* __restrict__ C) {
  // B fragments, bf16, MFMA operand order. Fragment f=(tile,lane) holds
  // B[k][n]: n=(tile&3)*32+(lane&31), k=(tile>>2)*16+(lane>>5)*8+reg.
  __shared__ ushortx8 lds_b[2048];   // 32 KiB, linear fragment order

  const int tid     = threadIdx.x;
  const int lane    = tid & 63;
  const int wave    = tid >> 6;            // 0..3
  const int colhalf = lane >> 5;
  const int koff    = colhalf * 8;         // k-offset within 16-wide k-step
  const int rbase   = wave * 32 + (lane & 31);

  // ---- Issue this block's A prefetch FIRST (longest latency: HBM) ----
  const int row0 = blockIdx.x * BM + wave * 32;
  const float* ap = A + (size_t)(row0 + (lane & 31)) * KDIM + koff;
  float4 apre[8];
#pragma unroll
  for (int kk = 0; kk < 4; ++kk) {
    apre[kk * 2]     = *(const float4*)(ap + kk * 16);
    apre[kk * 2 + 1] = *(const float4*)(ap + kk * 16 + 4);
  }

  // ---- In-kernel B staging: gather Emb (64 KB, L2-hot) -> LDS frags ----
  // 8 fragments per thread; linear ds_write_b128 is conflict-free.
#pragma unroll
  for (int i = 0; i < 8; ++i) {
    const int f    = tid + i * TPB;
    const int tile = f >> 6;
    const int fl   = f & 63;
    const int n    = ((tile & 3) << 5) + (fl & 31);
    const int k0   = ((tile >> 2) << 4) + ((fl >> 5) << 3);
    const float* ep = Emb + k0 * NDIM + n;
    float bv[8];
#pragma unroll
    for (int r = 0; r < 8; ++r) bv[r] = ep[r * NDIM];
    ushortx8 frag;
#pragma unroll
    for (int r = 0; r < 8; ++r) {
      __bf16 h = (__bf16)bv[r];
      frag[r] = *(unsigned short*)&h;
    }
    lds_b[f] = frag;
  }

  __syncthreads();   // one barrier: B staged (A prefetch also drained)

  const bf16x8* bbase = (const bf16x8*)lds_b;

  f32x16 acc0 = {}, acc1 = {}, acc2 = {}, acc3 = {};

  // kk = 0..3 from prefetch regs
#pragma unroll
  for (int kk = 0; kk < 4; ++kk) {
    const bf16x8 af = cvt_frag(apre[kk * 2], apre[kk * 2 + 1]);
    const int tb = (kk * 4) * 64 + lane;
    acc0 = __builtin_amdgcn_mfma_f32_32x32x16_bf16(af, bbase[tb +   0], acc0, 0, 0, 0);
    acc1 = __builtin_amdgcn_mfma_f32_32x32x16_bf16(af, bbase[tb +  64], acc1, 0, 0, 0);
    acc2 = __builtin_amdgcn_mfma_f32_32x32x16_bf16(af, bbase[tb + 128], acc2, 0, 0, 0);
    acc3 = __builtin_amdgcn_mfma_f32_32x32x16_bf16(af, bbase[tb + 192], acc3, 0, 0, 0);
  }

  // kk = 4..7 loaded inline (compiler hoists the independent loads early)
#pragma unroll
  for (int kk = 4; kk < 8; ++kk) {
    const float4 a0 = *(const float4*)(ap + kk * 16);
    const float4 a1 = *(const float4*)(ap + kk * 16 + 4);
    const bf16x8 af = cvt_frag(a0, a1);
    const int tb = (kk * 4) * 64 + lane;
    acc0 = __builtin_amdgcn_mfma_f32_32x32x16_bf16(af, bbase[tb +   0], acc0, 0, 0, 0);
    acc1 = __builtin_amdgcn_mfma_f32_32x32x16_bf16(af, bbase[tb +  64], acc1, 0, 0, 0);
    acc2 = __builtin_amdgcn_mfma_f32_32x32x16_bf16(af, bbase[tb + 128], acc2, 0, 0, 0);
    acc3 = __builtin_amdgcn_mfma_f32_32x32x16_bf16(af, bbase[tb + 192], acc3, 0, 0, 0);
  }

  // C layout (32x32 MFMA): col = lane&31, row = (reg&3)+8*(reg>>2)+4*colhalf.
  // Per store instruction the wave writes 2x128B contiguous full-line
  // segments. NT: C is write-once, keep it from evicting A in L2/L3.
  float* c0 = C + (size_t)row0 * NDIM + (lane & 31);
#pragma unroll
  for (int reg = 0; reg < 16; ++reg) {
    const int r = (reg & 3) + ((reg >> 2) << 3) + (colhalf << 2);
    float* cr = c0 + (size_t)r * NDIM;
    __builtin_nontemporal_store(acc0[reg], cr + 0);
    __builtin_nontemporal_store(acc1[reg], cr + 32);
    __builtin_nontemporal_store(acc2[reg], cr + 64);
    __builtin_nontemporal_store(acc3[reg], cr + 96);
  }
}

extern "C" void kernel_launch(void* const* d_in, const int* in_sizes, int n_in,
                              void* d_out, int out_size, void* d_ws, size_t ws_size,
                              hipStream_t stream) {
  const float* A   = (const float*)d_in[0];   // inputs  (B,S,I) fp32
  const float* Emb = (const float*)d_in[1];   // embedding (I,E) fp32
  float* out = (float*)d_out;                 // (B,S,E) fp32

  emb_gemm_kernel<<<dim3(GRID), dim3(TPB), 0, stream>>>(A, Emb, out);
}

// Round 9
// 44.511 us; speedup vs baseline: 1.0591x; 1.0591x over previous
//
#include <hip/hip_runtime.h>
#include <hip/hip_bf16.h>

// C[M,N] = A[M,K] * B[K,N]; M=262144, K=N=128; fp32 in/out, bf16 MFMA.
// FINAL (round-7 structure, best known: 44.6 us ≈ 95% of the 42.5 us
// compulsory-traffic roofline at 6.3 TB/s achievable HBM BW).
//   - single kernel: in-kernel B staging (Emb 64 KB, L2/L3-hot) into LDS
//     bf16 MFMA fragments via conflict-free linear ds_write_b128
//   - 8 waves/block, one barrier total, 2 tiles of 256 rows per block,
//     grid=512 (exactly 2 blocks/CU, VGPR-capped 16 waves/CU)
//   - A prefetch issued before staging; next-tile A loads overlap store drain
//   - NT scalar C stores: per wave-instruction 2x128 B contiguous full-line
//     segments; NT keeps write-once C from evicting A in L2/L3.
// Probed and rejected: NT A-loads (bypasses L2, -49%), transposed-operand
// float4 stores (partial-line HBM writes, WRITE_SIZE +83%), 4-wave/1-tile
// blocks (staging overhead, -6%), separate pack dispatch (+5 us launch gap).

typedef __bf16 bf16x8 __attribute__((ext_vector_type(8)));
typedef float  f32x16 __attribute__((ext_vector_type(16)));
typedef unsigned short ushortx8 __attribute__((ext_vector_type(8)));

#define M_TOTAL (64 * 4096)       // 262144 rows
#define KDIM 128
#define NDIM 128
#define TPB 512                   // 8 waves
#define BM 256                    // rows per tile (8 waves x 32 rows)
#define GRID 512                  // blocks; each does 2 tiles
#define TILES_PER_BLK 2

__device__ __forceinline__ bf16x8 cvt_frag(const float4 a0, const float4 a1) {
  bf16x8 af;
  af[0] = (__bf16)a0.x; af[1] = (__bf16)a0.y;
  af[2] = (__bf16)a0.z; af[3] = (__bf16)a0.w;
  af[4] = (__bf16)a1.x; af[5] = (__bf16)a1.y;
  af[6] = (__bf16)a1.z; af[7] = (__bf16)a1.w;
  return af;
}

__global__ __launch_bounds__(TPB) void emb_gemm_kernel(
    const float* __restrict__ A, const float* __restrict__ Emb,
    float* __restrict__ C) {
  // B fragments, bf16, MFMA operand order. Fragment f=(tile,lane) holds
  // B[k][n]: n=(tile&3)*32+(lane&31), k=(tile>>2)*16+(lane>>5)*8+reg.
  __shared__ ushortx8 lds_b[2048];   // 32 KiB, linear fragment order

  const int tid     = threadIdx.x;
  const int lane    = tid & 63;
  const int wave    = tid >> 6;            // 0..7
  const int colhalf = lane >> 5;
  const int koff    = colhalf * 8;         // k-offset within 16-wide k-step
  const int rbase   = wave * 32 + (lane & 31);

  // ---- Issue tile-0 A prefetch FIRST (longest latency: HBM) ----
  const float* ap0 = A + (size_t)(blockIdx.x * BM + rbase) * KDIM + koff;
  float4 apre[8];
#pragma unroll
  for (int kk = 0; kk < 4; ++kk) {
    apre[kk * 2]     = *(const float4*)(ap0 + kk * 16);
    apre[kk * 2 + 1] = *(const float4*)(ap0 + kk * 16 + 4);
  }

  // ---- In-kernel B staging: gather Emb (64 KB, L2/L3-hot) -> LDS frags ----
  float bval[4][8];
#pragma unroll
  for (int i = 0; i < 4; ++i) {
    const int f    = tid + i * TPB;
    const int tile = f >> 6;
    const int fl   = f & 63;
    const int n    = ((tile & 3) << 5) + (fl & 31);
    const int k0   = ((tile >> 2) << 4) + ((fl >> 5) << 3);
    const float* ep = Emb + k0 * NDIM + n;
#pragma unroll
    for (int r = 0; r < 8; ++r) bval[i][r] = ep[r * NDIM];
  }
#pragma unroll
  for (int i = 0; i < 4; ++i) {
    const int f = tid + i * TPB;
    ushortx8 frag;
#pragma unroll
    for (int r = 0; r < 8; ++r) {
      __bf16 h = (__bf16)bval[i][r];
      frag[r] = *(unsigned short*)&h;
    }
    lds_b[f] = frag;
  }

  __syncthreads();   // one barrier: B staged (and A prefetch drained)

  const bf16x8* bbase = (const bf16x8*)lds_b;

#pragma unroll 1
  for (int it = 0; it < TILES_PER_BLK; ++it) {
    const int mt   = blockIdx.x + it * GRID;         // tile index
    const int row0 = mt * BM + wave * 32;
    const float* ap = A + (size_t)(row0 + (lane & 31)) * KDIM + koff;

    f32x16 acc0 = {}, acc1 = {}, acc2 = {}, acc3 = {};

    // kk = 0..3 from prefetch regs
#pragma unroll
    for (int kk = 0; kk < 4; ++kk) {
      const bf16x8 af = cvt_frag(apre[kk * 2], apre[kk * 2 + 1]);
      const int tb = (kk * 4) * 64 + lane;
      acc0 = __builtin_amdgcn_mfma_f32_32x32x16_bf16(af, bbase[tb +   0], acc0, 0, 0, 0);
      acc1 = __builtin_amdgcn_mfma_f32_32x32x16_bf16(af, bbase[tb +  64], acc1, 0, 0, 0);
      acc2 = __builtin_amdgcn_mfma_f32_32x32x16_bf16(af, bbase[tb + 128], acc2, 0, 0, 0);
      acc3 = __builtin_amdgcn_mfma_f32_32x32x16_bf16(af, bbase[tb + 192], acc3, 0, 0, 0);
    }

    // kk = 4..7 loaded inline
#pragma unroll
    for (int kk = 4; kk < 8; ++kk) {
      const float4 a0 = *(const float4*)(ap + kk * 16);
      const float4 a1 = *(const float4*)(ap + kk * 16 + 4);
      const bf16x8 af = cvt_frag(a0, a1);
      const int tb = (kk * 4) * 64 + lane;
      acc0 = __builtin_amdgcn_mfma_f32_32x32x16_bf16(af, bbase[tb +   0], acc0, 0, 0, 0);
      acc1 = __builtin_amdgcn_mfma_f32_32x32x16_bf16(af, bbase[tb +  64], acc1, 0, 0, 0);
      acc2 = __builtin_amdgcn_mfma_f32_32x32x16_bf16(af, bbase[tb + 128], acc2, 0, 0, 0);
      acc3 = __builtin_amdgcn_mfma_f32_32x32x16_bf16(af, bbase[tb + 192], acc3, 0, 0, 0);
    }

    // Issue NEXT tile's first-half A loads now, overlapping the store drain.
    if (it + 1 < TILES_PER_BLK) {
      const float* apn = A + (size_t)((mt + GRID) * BM + rbase) * KDIM + koff;
#pragma unroll
      for (int kk = 0; kk < 4; ++kk) {
        apre[kk * 2]     = *(const float4*)(apn + kk * 16);
        apre[kk * 2 + 1] = *(const float4*)(apn + kk * 16 + 4);
      }
    }

    // C layout (32x32 MFMA): col = lane&31, row = (reg&3)+8*(reg>>2)+4*colhalf
    float* c0 = C + (size_t)row0 * NDIM + (lane & 31);
#pragma unroll
    for (int reg = 0; reg < 16; ++reg) {
      const int r = (reg & 3) + ((reg >> 2) << 3) + (colhalf << 2);
      float* cr = c0 + (size_t)r * NDIM;
      __builtin_nontemporal_store(acc0[reg], cr + 0);
      __builtin_nontemporal_store(acc1[reg], cr + 32);
      __builtin_nontemporal_store(acc2[reg], cr + 64);
      __builtin_nontemporal_store(acc3[reg], cr + 96);
    }
  }
}

extern "C" void kernel_launch(void* const* d_in, const int* in_sizes, int n_in,
                              void* d_out, int out_size, void* d_ws, size_t ws_size,
                              hipStream_t stream) {
  const float* A   = (const float*)d_in[0];   // inputs  (B,S,I) fp32
  const float* Emb = (const float*)d_in[1];   // embedding (I,E) fp32
  float* out = (float*)d_out;                 // (B,S,E) fp32

  emb_gemm_kernel<<<dim3(GRID), dim3(TPB), 0, stream>>>(A, Emb, out);
}